// Round 4
// baseline (1124.760 us; speedup 1.0000x reference)
//
#include <hip/hip_runtime.h>

// masksampling: outputs depend ONLY on initmask (x unused).
//   initmask: (32, 1, 512, 512) int (0..3)
//   out: mask1, mask2 each (32,3,1024,1024) f32, concatenated.
//
// full-res (r,col) value = PATTERNS[m][r&1][col&1], m = initmask[b, r>>1, col>>1]
// Equality LUTs, bit index = m*4 + (r&1)*2 + (col&1):
//   EQ1 (val==1) = 0x4821, EQ2 (val==2) = 0x1482
//
// Thread t owns float4 indices {2t, 2t+1} of EACH output: 8 full-res columns.
// One int4 mask load (4 cells) per thread. Nontemporal stores via clang native
// vector type (HIP_vector_type is rejected by the builtin).

typedef float f32x4 __attribute__((ext_vector_type(4)));
typedef int   i32x4 __attribute__((ext_vector_type(4)));

#define N_F4_PER_OUT 25165824u   // 32*3*1024*1024/4
#define N_THREADS (N_F4_PER_OUT / 2u)

__global__ __launch_bounds__(256) void masksampling_kernel(const int* __restrict__ im,
                                                           float* __restrict__ out) {
    const unsigned t  = blockIdx.x * 256u + threadIdx.x;  // 0 .. 12,582,911
    const unsigned j8 = t & 127u;            // col group of 8 (cols 8j..8j+7)
    const unsigned r  = (t >> 7) & 1023u;    // full-res row
    const unsigned bc = t >> 17;             // b*3 + c, 0..95
    const unsigned b  = bc / 3u;

    // int4 mask index: (b*512 + r/2)*128 + j8
    const i32x4 m4 = ((const i32x4*)im)[b * 65536u + (r >> 1) * 128u + j8];

    const unsigned base = (r & 1u) * 2u;
    const unsigned sx = (unsigned)m4.x * 4u + base;
    const unsigned sy = (unsigned)m4.y * 4u + base;
    const unsigned sz = (unsigned)m4.z * 4u + base;
    const unsigned sw = (unsigned)m4.w * 4u + base;

    const unsigned EQ1 = 0x4821u, EQ2 = 0x1482u;
    f32x4 f1a, f1b, f2a, f2b;
    f1a.x = (float)((EQ1 >> sx) & 1u); f1a.y = (float)((EQ1 >> (sx + 1u)) & 1u);
    f1a.z = (float)((EQ1 >> sy) & 1u); f1a.w = (float)((EQ1 >> (sy + 1u)) & 1u);
    f1b.x = (float)((EQ1 >> sz) & 1u); f1b.y = (float)((EQ1 >> (sz + 1u)) & 1u);
    f1b.z = (float)((EQ1 >> sw) & 1u); f1b.w = (float)((EQ1 >> (sw + 1u)) & 1u);
    f2a.x = (float)((EQ2 >> sx) & 1u); f2a.y = (float)((EQ2 >> (sx + 1u)) & 1u);
    f2a.z = (float)((EQ2 >> sy) & 1u); f2a.w = (float)((EQ2 >> (sy + 1u)) & 1u);
    f2b.x = (float)((EQ2 >> sz) & 1u); f2b.y = (float)((EQ2 >> (sz + 1u)) & 1u);
    f2b.z = (float)((EQ2 >> sw) & 1u); f2b.w = (float)((EQ2 >> (sw + 1u)) & 1u);

    f32x4* o1 = (f32x4*)out;
    f32x4* o2 = o1 + N_F4_PER_OUT;
    const unsigned idx = 2u * t;
    __builtin_nontemporal_store(f1a, &o1[idx]);
    __builtin_nontemporal_store(f1b, &o1[idx + 1u]);
    __builtin_nontemporal_store(f2a, &o2[idx]);
    __builtin_nontemporal_store(f2b, &o2[idx + 1u]);
}

extern "C" void kernel_launch(void* const* d_in, const int* in_sizes, int n_in,
                              void* d_out, int out_size, void* d_ws, size_t ws_size,
                              hipStream_t stream) {
    const int* im = (const int*)d_in[1];   // d_in[0] = x (unused)
    float* out = (float*)d_out;
    masksampling_kernel<<<N_THREADS / 256u, 256, 0, stream>>>(im, out);
}

// Round 5
// 974.156 us; speedup vs baseline: 1.1546x; 1.1546x over previous
//
#include <hip/hip_runtime.h>

// masksampling: outputs depend ONLY on initmask (x unused).
//   initmask: (32, 1, 512, 512) int (0..3)
//   d_out: mask1 ‖ mask2, each (32,3,1024,1024) f32, contiguous.
//
// full-res (r,col) value = PATTERNS[m][r&1][col&1], m = initmask[b, r>>1, col>>1]
// Equality LUTs, bit index = m*4 + (r&1)*2 + (col&1):
//   EQ1 (val==1) = 0x4821, EQ2 (val==2) = 0x1482
//
// SINGLE LINEAR WRITE STREAM: thread t writes float4 index t of the
// concatenated output — identical store pattern to the 6.35 TB/s fillBuffer.
// The two halves differ only in which EQ constant is used (uniform select).
// Plain stores (NT stores regressed +184 µs in R4 — L2 write-combining helps).

typedef float f32x4 __attribute__((ext_vector_type(4)));

#define N_F4_PER_OUT 25165824u                 // 32*3*1024*1024/4 (= 3 * 2^23)
#define N_TOTAL      (2u * N_F4_PER_OUT)       // 50,331,648 float4 stores

__global__ __launch_bounds__(256) void masksampling_kernel(const int* __restrict__ im,
                                                           float* __restrict__ out) {
    const unsigned t = blockIdx.x * 256u + threadIdx.x;   // 0 .. 50,331,647

    // Which output half (wave-uniform except one boundary wave).
    const bool second = (t >= N_F4_PER_OUT);
    const unsigned EQ = second ? 0x1482u : 0x4821u;
    const unsigned u  = second ? t - N_F4_PER_OUT : t;    // index within one output

    const unsigned j  = u & 255u;           // col group of 4 (cols 4j..4j+3)
    const unsigned r  = (u >> 8) & 1023u;   // full-res row
    const unsigned bc = u >> 18;            // b*3 + c, 0..95
    const unsigned b  = bc / 3u;            // compiler magic-mul

    // mask int2 index: (b*512 + r/2)*256 + j  (cells 2j, 2j+1 of mask row r/2)
    const int2 m2 = ((const int2*)im)[b * 131072u + (r >> 1) * 256u + j];

    const unsigned base = (r & 1u) * 2u;
    const unsigned s0 = (unsigned)m2.x * 4u + base;   // cols 4j, 4j+1
    const unsigned s1 = (unsigned)m2.y * 4u + base;   // cols 4j+2, 4j+3

    f32x4 f;
    f.x = (float)((EQ >> s0) & 1u);
    f.y = (float)((EQ >> (s0 + 1u)) & 1u);
    f.z = (float)((EQ >> s1) & 1u);
    f.w = (float)((EQ >> (s1 + 1u)) & 1u);

    ((f32x4*)out)[t] = f;
}

extern "C" void kernel_launch(void* const* d_in, const int* in_sizes, int n_in,
                              void* d_out, int out_size, void* d_ws, size_t ws_size,
                              hipStream_t stream) {
    const int* im = (const int*)d_in[1];   // d_in[0] = x (unused)
    float* out = (float*)d_out;
    masksampling_kernel<<<N_TOTAL / 256u, 256, 0, stream>>>(im, out);
}